// Round 6
// baseline (185.037 us; speedup 1.0000x reference)
//
#include <hip/hip_runtime.h>
#include <math.h>

#define TOKENS    1024
#define IN_W      512
#define BLOCK_H   256
#define OUT_W     512
#define N_EXPERTS 64
#define TOPK      2
#define NSLOTS    (TOKENS * TOPK)
#define LIST_CAP  128     // ne ~ Binom(2048,1/64): mean 32, sigma 5.6
#define T_GRP     12      // tokens per expert-block chunk
#define NGRP      4       // groups per expert -> 256 blocks = 1/CU
#define XPAD      520     // x row stride (floats); 2080 B, 16B-aligned
#define OSPAD     516     // out-stage row stride; 2064 B, 16B-aligned (aliases xs)
#define VPAD      264     // v row stride; 1056 B, 16B-aligned

// ---------------------------------------------------------------------------
// Routing + fused compaction (unchanged from round 5; ~3-5 us).
// ---------------------------------------------------------------------------
__global__ __launch_bounds__(256) void routing_kernel(
    const float* __restrict__ x, const float* __restrict__ noise,
    const float* __restrict__ mixer, const float* __restrict__ noisec,
    float* __restrict__ esc, int* __restrict__ counts, int* __restrict__ lists)
{
    __shared__ float xs[2 * 512];
    __shared__ float pm[2 * 2 * 64];
    __shared__ float pn[2 * 2 * 64];
    const int blk  = blockIdx.x;
    const int tid  = threadIdx.x;
    const int wave = tid >> 6, lane = tid & 63;
    const int tq = wave >> 1;
    const int ih = wave & 1;

    ((float4*)xs)[tid] = ((const float4*)x)[(size_t)blk * 256 + tid];
    __syncthreads();

    float am = 0.f, an = 0.f;
    const float* xp = xs + tq * 512 + ih * 256;
    const float* mp = mixer  + (size_t)(ih * 256) * 64 + lane;
    const float* np = noisec + (size_t)(ih * 256) * 64 + lane;
    #pragma unroll 8
    for (int i = 0; i < 256; ++i) {
        const float xv = xp[i];
        am = fmaf(xv, mp[i * 64], am);
        an = fmaf(xv, np[i * 64], an);
    }
    pm[tq * 128 + ih * 64 + lane] = am;
    pn[tq * 128 + ih * 64 + lane] = an;
    __syncthreads();

    if (tid < 128) {
        const int e = tid & 63, tt = tid >> 6;
        const int t = blk * 2 + tt;
        const float am2 = pm[tt * 128 + e] + pm[tt * 128 + 64 + e];
        const float an2 = pn[tt * 128 + e] + pn[tt * 128 + 64 + e];
        const float sp = fmaxf(an2, 0.f) + log1pf(expf(-fabsf(an2)));
        pm[tt * 128 + e] = am2 + noise[(size_t)t * 64 + e] * sp;
    }
    __syncthreads();

    if (tid < 2) {
        const float* h = pm + tid * 128;
        float b0 = -INFINITY, b1 = -INFINITY;
        int i0 = 0, i1 = 0;
        for (int i = 0; i < N_EXPERTS; ++i) {
            const float v = h[i];
            if (v > b0)      { b1 = b0; i1 = i0; b0 = v; i0 = i; }  // strict >: stable ties
            else if (v > b1) { b1 = v; i1 = i; }
        }
        const float z   = expf(b1 - b0);
        const float inv = 1.f / (1.f + z);
        const int t = blk * 2 + tid;
        esc[t * 2 + 0] = inv;
        esc[t * 2 + 1] = z * inv;
        const int p0 = atomicAdd(&counts[i0], 1);
        if (p0 < LIST_CAP) lists[i0 * LIST_CAP + p0] = t * 2 + 0;
        const int p1 = atomicAdd(&counts[i1], 1);
        if (p1 < LIST_CAP) lists[i1 * LIST_CAP + p1] = t * 2 + 1;
    }
}

// ---------------------------------------------------------------------------
// Fused expert FFN. grid (64 experts, NGRP) = 256 blocks (1/CU), 1024 thr.
// Changes vs round 5 (which was latency-bound, VALUBusy 19%):
//  - 4-deep float4 prefetch ring on the weight stream (~8 loads in flight;
//    one full iteration of issue distance before consumption).
//  - lane K-rows now CONSECUTIVE (r4 = (lane>>4)*4) so x/v LDS reads are one
//    ds_read_b128 per 16 K-rows instead of 4x ds_read_b32.
//  - phase 2 tiled as 8 col-octants x 2 token-sextets, same 16x4 lane map.
// Global coalescing unchanged: each weight instr = 4 rows x 256 B = 1 KB.
// ---------------------------------------------------------------------------
__global__ __launch_bounds__(1024, 4) void expert_kernel(
    const float* __restrict__ x,
    const float* __restrict__ w1s, const float* __restrict__ b1s,
    const float* __restrict__ w2s, const float* __restrict__ b2s,
    const int* __restrict__ counts, const int* __restrict__ lists,
    const float* __restrict__ esc, float* __restrict__ out)
{
    __shared__ __align__(16) float smem[T_GRP * XPAD];  // xs, then os (aliased)
    __shared__ __align__(16) float vsm[T_GRP * VPAD];
    __shared__ int   slotIds[T_GRP];
    __shared__ float escv[T_GRP];

    const int e  = blockIdx.x;
    const int g  = blockIdx.y;
    const int ne = min(counts[e], LIST_CAP);
    const int tid  = threadIdx.x;
    const int wave = tid >> 6, lane = tid & 63;

    const int c4 = lane & 15;            // float4-col within 16-col group
    const int r4 = (lane >> 4) << 2;     // 4 consecutive K-rows {4r..4r+3}
    // phase-1 roles: 4 col-quarters (64 of 256 hidden cols) x 4 token-triples
    const int cq1   = wave & 3;
    const int t0_1  = (wave >> 2) * 3;
    const int wcol1 = cq1 * 16 + c4;
    // phase-2 roles: 8 col-octants (64 of 512 out cols) x 2 token-sextets
    const int co2   = wave & 7;
    const int t0_2  = (wave >> 3) * 6;
    const int wcol2 = co2 * 16 + c4;

    const float4* w1v = (const float4*)(w1s + (size_t)e * IN_W * BLOCK_H);
    const float4* w2v = (const float4*)(w2s + (size_t)e * BLOCK_H * OUT_W);
    const float4* b1v = (const float4*)(b1s + (size_t)e * BLOCK_H);
    const float4* b2v = (const float4*)(b2s + (size_t)e * OUT_W);
    const float4* x4  = (const float4*)x;

    for (int base = g * T_GRP; base < ne; base += NGRP * T_GRP) {
        const int nTok = min(T_GRP, ne - base);
        if (tid < T_GRP) {
            const int s = (tid < nTok) ? lists[e * LIST_CAP + base + tid] : 0;
            slotIds[tid] = s;
            escv[tid]    = esc[s];
        }
        __syncthreads();

        for (int idx = tid; idx < T_GRP * 128; idx += 1024) {
            const int t = idx >> 7, q = idx & 127;
            float4 v = make_float4(0.f, 0.f, 0.f, 0.f);
            if (t < nTok) v = x4[(size_t)(slotIds[t] >> 1) * 128 + q];
            *(float4*)&smem[t * XPAD + q * 4] = v;
        }
        __syncthreads();

        // ---- phase 1: v = relu(x @ W1 + b1), 3 tokens x 4 cols/thread ----
        {
            float4 a0 = make_float4(0.f,0.f,0.f,0.f), a1 = a0, a2 = a0;
            const float4* wp  = w1v + (size_t)r4 * 64 + wcol1;
            const float*  xr0 = smem + (t0_1 + 0) * XPAD + r4;
            const float*  xr1 = smem + (t0_1 + 1) * XPAD + r4;
            const float*  xr2 = smem + (t0_1 + 2) * XPAD + r4;
            float4 wb[4], wc[4];
            #pragma unroll
            for (int k = 0; k < 4; ++k) wb[k] = wp[(size_t)k * 64];
            for (int i = 0; i < IN_W; i += 16) {
                #pragma unroll
                for (int k = 0; k < 4; ++k) wc[k] = wb[k];
                if (i + 16 < IN_W) {
                    #pragma unroll
                    for (int k = 0; k < 4; ++k)
                        wb[k] = wp[(size_t)(i + 16 + k) * 64];
                }
                const float4 xv0 = *(const float4*)(xr0 + i);   // ds_read_b128
                const float4 xv1 = *(const float4*)(xr1 + i);
                const float4 xv2 = *(const float4*)(xr2 + i);
                const float* f0 = (const float*)&xv0;
                const float* f1 = (const float*)&xv1;
                const float* f2 = (const float*)&xv2;
                #pragma unroll
                for (int k = 0; k < 4; ++k) {
                    const float4 w = wc[k];
                    a0.x = fmaf(f0[k], w.x, a0.x); a0.y = fmaf(f0[k], w.y, a0.y);
                    a0.z = fmaf(f0[k], w.z, a0.z); a0.w = fmaf(f0[k], w.w, a0.w);
                    a1.x = fmaf(f1[k], w.x, a1.x); a1.y = fmaf(f1[k], w.y, a1.y);
                    a1.z = fmaf(f1[k], w.z, a1.z); a1.w = fmaf(f1[k], w.w, a1.w);
                    a2.x = fmaf(f2[k], w.x, a2.x); a2.y = fmaf(f2[k], w.y, a2.y);
                    a2.z = fmaf(f2[k], w.z, a2.z); a2.w = fmaf(f2[k], w.w, a2.w);
                }
            }
            // reduce across the 4 row-groups (lanes differing in bits 4,5)
            #pragma unroll
            for (int m = 16; m <= 32; m <<= 1) {
                a0.x += __shfl_xor(a0.x, m); a0.y += __shfl_xor(a0.y, m);
                a0.z += __shfl_xor(a0.z, m); a0.w += __shfl_xor(a0.w, m);
                a1.x += __shfl_xor(a1.x, m); a1.y += __shfl_xor(a1.y, m);
                a1.z += __shfl_xor(a1.z, m); a1.w += __shfl_xor(a1.w, m);
                a2.x += __shfl_xor(a2.x, m); a2.y += __shfl_xor(a2.y, m);
                a2.z += __shfl_xor(a2.z, m); a2.w += __shfl_xor(a2.w, m);
            }
            if (lane < 16) {
                const float4 bb = b1v[wcol1];
                float4 r;
                r.x = fmaxf(a0.x + bb.x, 0.f); r.y = fmaxf(a0.y + bb.y, 0.f);
                r.z = fmaxf(a0.z + bb.z, 0.f); r.w = fmaxf(a0.w + bb.w, 0.f);
                *(float4*)&vsm[(t0_1 + 0) * VPAD + wcol1 * 4] = r;
                r.x = fmaxf(a1.x + bb.x, 0.f); r.y = fmaxf(a1.y + bb.y, 0.f);
                r.z = fmaxf(a1.z + bb.z, 0.f); r.w = fmaxf(a1.w + bb.w, 0.f);
                *(float4*)&vsm[(t0_1 + 1) * VPAD + wcol1 * 4] = r;
                r.x = fmaxf(a2.x + bb.x, 0.f); r.y = fmaxf(a2.y + bb.y, 0.f);
                r.z = fmaxf(a2.z + bb.z, 0.f); r.w = fmaxf(a2.w + bb.w, 0.f);
                *(float4*)&vsm[(t0_1 + 2) * VPAD + wcol1 * 4] = r;
            }
        }
        __syncthreads();   // xs consumed; os may alias smem

        // ---- phase 2: os = v @ W2, 6 tokens x 4 cols/thread ----
        {
            float4 acc[6];
            #pragma unroll
            for (int j = 0; j < 6; ++j) acc[j] = make_float4(0.f,0.f,0.f,0.f);
            const float4* wp2 = w2v + (size_t)r4 * 128 + wcol2;
            const float*  vr  = vsm + t0_2 * VPAD + r4;
            float4 wb[4], wc[4];
            #pragma unroll
            for (int k = 0; k < 4; ++k) wb[k] = wp2[(size_t)k * 128];
            for (int h = 0; h < BLOCK_H; h += 16) {
                #pragma unroll
                for (int k = 0; k < 4; ++k) wc[k] = wb[k];
                if (h + 16 < BLOCK_H) {
                    #pragma unroll
                    for (int k = 0; k < 4; ++k)
                        wb[k] = wp2[(size_t)(h + 16 + k) * 128];
                }
                float4 vv[6];
                #pragma unroll
                for (int j = 0; j < 6; ++j)
                    vv[j] = *(const float4*)(vr + j * VPAD + h);  // ds_read_b128
                #pragma unroll
                for (int k = 0; k < 4; ++k) {
                    const float4 w = wc[k];
                    #pragma unroll
                    for (int j = 0; j < 6; ++j) {
                        const float s = ((const float*)&vv[j])[k];
                        acc[j].x = fmaf(s, w.x, acc[j].x);
                        acc[j].y = fmaf(s, w.y, acc[j].y);
                        acc[j].z = fmaf(s, w.z, acc[j].z);
                        acc[j].w = fmaf(s, w.w, acc[j].w);
                    }
                }
            }
            #pragma unroll
            for (int m = 16; m <= 32; m <<= 1) {
                #pragma unroll
                for (int j = 0; j < 6; ++j) {
                    acc[j].x += __shfl_xor(acc[j].x, m);
                    acc[j].y += __shfl_xor(acc[j].y, m);
                    acc[j].z += __shfl_xor(acc[j].z, m);
                    acc[j].w += __shfl_xor(acc[j].w, m);
                }
            }
            if (lane < 16) {
                #pragma unroll
                for (int j = 0; j < 6; ++j)
                    *(float4*)&smem[(t0_2 + j) * OSPAD + wcol2 * 4] = acc[j];
            }
        }
        __syncthreads();

        // ---- epilogue: out += sc * (os + b2) ----
        for (int idx = tid; idx < T_GRP * 128; idx += 1024) {
            const int t = idx >> 7, q = idx & 127;
            if (t < nTok) {
                const float4 r  = *(const float4*)&smem[t * OSPAD + q * 4];
                const float4 bb = b2v[q];
                const float  sc = escv[t];
                float* o = out + (size_t)(slotIds[t] >> 1) * OUT_W + q * 4;
                atomicAdd(o + 0, (r.x + bb.x) * sc);
                atomicAdd(o + 1, (r.y + bb.y) * sc);
                atomicAdd(o + 2, (r.z + bb.z) * sc);
                atomicAdd(o + 3, (r.w + bb.w) * sc);
            }
        }
        __syncthreads();
    }
}

extern "C" void kernel_launch(void* const* d_in, const int* in_sizes, int n_in,
                              void* d_out, int out_size, void* d_ws, size_t ws_size,
                              hipStream_t stream) {
    const float* x      = (const float*)d_in[0];
    const float* noise  = (const float*)d_in[1];
    const float* w1s    = (const float*)d_in[2];
    const float* b1s    = (const float*)d_in[3];
    const float* w2s    = (const float*)d_in[4];
    const float* b2s    = (const float*)d_in[5];
    const float* mixer  = (const float*)d_in[6];
    const float* noisec = (const float*)d_in[7];
    float* out = (float*)d_out;

    // workspace: ~41 KB total (keep far under ws_size; round 2's 2.2 MB
    // layout overran d_ws and corrupted adjacent allocations)
    char* ws = (char*)d_ws;
    int*   counts = (int*)ws;                       ws += 256;
    float* esc    = (float*)ws;                     ws += NSLOTS * sizeof(float);
    int*   lists  = (int*)ws;   /* 64 * 128 ints = 32 KB */

    hipMemsetAsync(d_out, 0, (size_t)out_size * sizeof(float), stream);
    hipMemsetAsync(counts, 0, 256, stream);

    routing_kernel<<<TOKENS / 2, 256, 0, stream>>>(x, noise, mixer, noisec,
                                                   esc, counts, lists);
    expert_kernel<<<dim3(N_EXPERTS, NGRP), 1024, 0, stream>>>(
        x, w1s, b1s, w2s, b2s, counts, lists, esc, out);
}